// Round 13
// baseline (841.256 us; speedup 1.0000x reference)
//
#include <hip/hip_runtime.h>
#include <hip/hip_bf16.h>
#include <cstdint>
#include <cstddef>

#define N_NODES 50000
#define N_EDGES 800000
#define IN_CH 64
#define HID_CH 128
#define N_GRAPHS 64

#define NB_CNT8 ((N_EDGES + 2047) / 2048)        // 391 (8 edges/thread)
#define NB_CNT4 ((N_EDGES + 1023) / 1024)        // 782 (4 edges/thread, scatter)
#define NB_GEMM ((N_NODES + 63) / 64)            // 782
#define W_ELEMS (4 * IN_CH * 128 + 4 * HID_CH * 128)  // 98304
#define NB_CONV ((W_ELEMS + 255) / 256)          // 384
#define NB_BND  ((N_NODES + 1 + 255) / 256)      // 196 (graph-boundary stage)
#define BUCKET 64                                 // edge slots per dst (P(deg>64)~1e-18)

typedef short s16x8 __attribute__((ext_vector_type(8)));
typedef float f32x4 __attribute__((ext_vector_type(4)));
typedef float f32x2 __attribute__((ext_vector_type(2)));

__device__ __forceinline__ float bf2f(__hip_bfloat16 v) { return __bfloat162float(v); }
__device__ __forceinline__ float bfbits2f(unsigned hs) {
  union { unsigned u; float f; } v; v.u = hs << 16; return v.f;
}
__device__ __forceinline__ float bfhi2f(unsigned w) {
  union { unsigned u; float f; } v; v.u = w & 0xffff0000u; return v.f;
}
__device__ __forceinline__ short f2bfs(float f) {
  __hip_bfloat16 h = __float2bfloat16(f); return *(short*)&h;
}
__device__ __forceinline__ unsigned short f2bfu(float f) {
  __hip_bfloat16 h = __float2bfloat16(f); return *(unsigned short*)&h;
}
__device__ __forceinline__ int clamp_id(int v) {
  if (v < 0) v = 0;
  if (v >= N_NODES) v = N_NODES - 1;
  return v;
}

// fp8 e4m3 (OCP) pack/unpack via gfx950 HW converters (word-selects are immediates).
__device__ __forceinline__ unsigned char f2fp8(float v) {
  return (unsigned char)(__builtin_amdgcn_cvt_pk_fp8_f32(v, v, 0, false) & 0xff);
}
template<bool HI>
__device__ __forceinline__ f32x2 fp8pair(unsigned w) {
  return __builtin_amdgcn_cvt_pk_f32_fp8(w, HI);
}

// R6: packed 2-wide f32 math (CDNA VOP3P). hipcc does not emit these from scalar
// source; non-volatile asm so the scheduler can interleave them freely.
__device__ __forceinline__ f32x2 pkfma(f32x2 a, f32x2 b, f32x2 c) {
  f32x2 d;
  asm("v_pk_fma_f32 %0, %1, %2, %3" : "=v"(d) : "v"(a), "v"(b), "v"(c));
  return d;
}
__device__ __forceinline__ f32x2 pkadd(f32x2 a, f32x2 b) {
  f32x2 d;
  asm("v_pk_add_f32 %0, %1, %2" : "=v"(d) : "v"(a), "v"(b));
  return d;
}

// R7: 4-lane quad sum on the VALU via DPP quad_perm (hand-verified).
__device__ __forceinline__ float quad_sum(float d) {
  d += __int_as_float(__builtin_amdgcn_mov_dpp(__float_as_int(d), 0xB1, 0xf, 0xf, true));
  d += __int_as_float(__builtin_amdgcn_mov_dpp(__float_as_int(d), 0x4E, 0xf, 0xf, true));
  return d;
}

// R12: async global->LDS DMA, 16B/lane. LDS dest is wave-uniform base + lane*16.
__device__ __forceinline__ void gload_lds16(const void* g, void* l) {
  __builtin_amdgcn_global_load_lds(
      (const __attribute__((address_space(1))) unsigned int*)g,
      (__attribute__((address_space(3))) unsigned int*)l, 16, 0, 0);
}

// ---------------- A: degree-count(+rank) + weights + graph boundaries ----------------
// (R1: atomicAdd return value saved as intra-segment rank. R9: rank indexes a fixed
// 64-slot bucket per dst — no prefix scan. R10: gstart precomputed. R13: count at
// 8 edges/thread for deeper MLP on the atomic chain.)
__global__ __launch_bounds__(256)
void prep(const int* __restrict__ ei, int* __restrict__ cnt,
          unsigned short* __restrict__ rank,
          const int* __restrict__ batch, int* __restrict__ gstart,
          const float* __restrict__ w1q, const float* __restrict__ w1k,
          const float* __restrict__ w1v, const float* __restrict__ w1s,
          const float* __restrict__ w2q, const float* __restrict__ w2k,
          const float* __restrict__ w2v, const float* __restrict__ w2s,
          __hip_bfloat16* d1q, __hip_bfloat16* d1k, __hip_bfloat16* d1v, __hip_bfloat16* d1s,
          __hip_bfloat16* d2q, __hip_bfloat16* d2k, __hip_bfloat16* d2v, __hip_bfloat16* d2s)
{
  int bx = blockIdx.x;
  if (bx < NB_CNT8) {
    int e0 = bx * 2048 + threadIdx.x * 8;
    if (e0 >= N_EDGES) return;
    if (e0 + 7 < N_EDGES) {
      int4 dv0 = *(const int4*)(ei + N_EDGES + e0);
      int4 dv1 = *(const int4*)(ei + N_EDGES + e0 + 4);
      ushort4 ra, rb;
      ra.x = (unsigned short)atomicAdd(&cnt[clamp_id(dv0.x)], 1);
      ra.y = (unsigned short)atomicAdd(&cnt[clamp_id(dv0.y)], 1);
      ra.z = (unsigned short)atomicAdd(&cnt[clamp_id(dv0.z)], 1);
      ra.w = (unsigned short)atomicAdd(&cnt[clamp_id(dv0.w)], 1);
      rb.x = (unsigned short)atomicAdd(&cnt[clamp_id(dv1.x)], 1);
      rb.y = (unsigned short)atomicAdd(&cnt[clamp_id(dv1.y)], 1);
      rb.z = (unsigned short)atomicAdd(&cnt[clamp_id(dv1.z)], 1);
      rb.w = (unsigned short)atomicAdd(&cnt[clamp_id(dv1.w)], 1);
      *(ushort4*)(rank + e0) = ra;
      *(ushort4*)(rank + e0 + 4) = rb;
    } else {
      for (int j = 0; j < 8; ++j)
        if (e0 + j < N_EDGES)
          rank[e0 + j] = (unsigned short)atomicAdd(&cnt[clamp_id(ei[N_EDGES + e0 + j])], 1);
    }
    return;
  }
  if (bx < NB_CNT8 + NB_CONV) {
    int j = (bx - NB_CNT8) * 256 + threadIdx.x;
    if (j >= W_ELEMS) return;
    const float* S[8] = {w1q, w1k, w1v, w1s, w2q, w2k, w2v, w2s};
    __hip_bfloat16* D[8] = {d1q, d1k, d1v, d1s, d2q, d2k, d2v, d2s};
    int m, r;
    if (j < 4 * IN_CH * 128) { m = j >> 13; r = j & 8191; }
    else { int jj = j - 4 * IN_CH * 128; m = 4 + (jj >> 14); r = jj & 16383; }
    int k = r >> 7, c = r & 127;
    D[m][(((k >> 3) * 128 + c) << 3) + (k & 7)] = __float2bfloat16(S[m][r]);
    return;
  }
  // graph-boundary stage: gstart[g] = first i with batch[i] >= g; gstart[G] = N.
  int i = (bx - NB_CNT8 - NB_CONV) * 256 + threadIdx.x;
  if (i > N_NODES) return;
  int bl = (i > 0) ? min(max(batch[i - 1], 0), N_GRAPHS - 1) : -1;
  int bc = (i < N_NODES) ? min(max(batch[i], 0), N_GRAPHS - 1) : N_GRAPHS;
  for (int g = bl + 1; g <= bc; ++g) gstart[g] = i;
}

// ---------------- shared gemm body (R12: global_load_lds + 16KB-chunk dbuf) ----------------
// Outputs: mat0=Q (bf16, row 128), mat1=K, mat2=V -> KV8 row, mat3=S (bf16, row 128).
// R7: KV8 row INTERLEAVED in 16B groups (K ch 8g..8g+7 | V same) — attn reads one uint4.
// So may alias X (in-place per-row: A-frags register-resident before stores).
template<int KD, int XF32>
__device__ __forceinline__ void gemm_body(
    int bg, const void* X,
    const short* __restrict__ WTq, const short* __restrict__ WTk,
    const short* __restrict__ WTv, const short* __restrict__ WTs,
    const float* __restrict__ bq, const float* __restrict__ bk,
    const float* __restrict__ bv, const float* __restrict__ bs,
    short* Qo, unsigned char* KV8, short* So, short* lds /* 2 x 8192 shorts */)
{
  constexpr int KT = KD / 32;
  constexpr int HALVES = KD / 64;          // 16KB chunks per mat: 1 (gemm1) / 2 (gemm2)
  constexpr int STEPS = 4 * HALVES;
  const int tid  = threadIdx.x;
  const int wid  = tid >> 6;
  const int lane = tid & 63;
  const int quad = lane >> 4;
  const int mm   = lane & 15;
  const int rt   = wid & 1;
  const int ch   = wid >> 1;
  const int rowbase = bg * 64 + rt * 32;

  const short* wts[4] = {WTq, WTk, WTv, WTs};
  const float* bias[4] = {bq, bk, bv, bs};

  auto stage = [&](int s) {
    const short* src = wts[s / HALVES] + (s % HALVES) * 8192;
    short* dstb = lds + (s & 1) * 8192;
    #pragma unroll
    for (int i = 0; i < 4; ++i)
      gload_lds16(src + (size_t)(i * 256 + tid) * 8,
                  dstb + (size_t)(i * 256 + wid * 64) * 8);
  };

  stage(0);

  s16x8 afrag[2][KT];
  #pragma unroll
  for (int t = 0; t < 2; ++t) {
    const int arow = rowbase + t * 16 + mm;
    if (arow < N_NODES) {
      if (XF32) {
        const float* xp = (const float*)X + (size_t)arow * KD;
        #pragma unroll
        for (int kt = 0; kt < KT; ++kt) {
          const float4* p = (const float4*)(xp + kt * 32 + quad * 8);
          float4 a = p[0], b = p[1];
          s16x8 fr;
          fr[0] = f2bfs(a.x); fr[1] = f2bfs(a.y); fr[2] = f2bfs(a.z); fr[3] = f2bfs(a.w);
          fr[4] = f2bfs(b.x); fr[5] = f2bfs(b.y); fr[6] = f2bfs(b.z); fr[7] = f2bfs(b.w);
          afrag[t][kt] = fr;
        }
      } else {
        const short* xp = (const short*)X + (size_t)arow * KD;
        #pragma unroll
        for (int kt = 0; kt < KT; ++kt)
          afrag[t][kt] = *(const s16x8*)(xp + kt * 32 + quad * 8);
      }
    } else {
      #pragma unroll
      for (int kt = 0; kt < KT; ++kt)
        afrag[t][kt] = (s16x8){0,0,0,0,0,0,0,0};
    }
  }

  __syncthreads();   // drains stage(0); afrag loads overlapped it

  f32x4 acc[4][2];
  #pragma unroll
  for (int s = 0; s < STEPS; ++s) {
    const int mat  = s / HALVES;
    const int half = s % HALVES;
    const short* bufp = lds + (s & 1) * 8192;

    if (half == 0) {
      #pragma unroll
      for (int c4 = 0; c4 < 4; ++c4) {
        float b = bias[mat][ch * 64 + c4 * 16 + mm];
        f32x4 av = {b, b, b, b};
        acc[c4][0] = av; acc[c4][1] = av;
      }
    }
    if (s + 1 < STEPS) stage(s + 1);   // issue next chunk BEFORE compute

    #pragma unroll
    for (int ktl = 0; ktl < 2; ++ktl) {
      #pragma unroll
      for (int c4 = 0; c4 < 4; ++c4) {
        s16x8 bfrag = *(const s16x8*)(bufp + ((((ktl * 4 + quad) << 7) + ch * 64 + c4 * 16 + mm) << 3));
        acc[c4][0] = __builtin_amdgcn_mfma_f32_16x16x32_bf16(afrag[0][half * 2 + ktl], bfrag, acc[c4][0], 0, 0, 0);
        acc[c4][1] = __builtin_amdgcn_mfma_f32_16x16x32_bf16(afrag[1][half * 2 + ktl], bfrag, acc[c4][1], 0, 0, 0);
      }
    }

    if (half == HALVES - 1) {
      if (mat == 1 || mat == 2) {
        const int voff = (mat == 2) ? 8 : 0;
        #pragma unroll
        for (int c4 = 0; c4 < 4; ++c4) {
          const int col = ch * 64 + c4 * 16 + mm;
          const int bpos = ((col >> 3) << 4) + voff + (col & 7);  // interleaved KV byte
          #pragma unroll
          for (int t = 0; t < 2; ++t) {
            #pragma unroll
            for (int r = 0; r < 4; ++r) {
              int row = rowbase + t * 16 + quad * 4 + r;
              if (row < N_NODES)
                KV8[(size_t)row * 256 + bpos] = f2fp8(acc[c4][t][r]);
            }
          }
        }
      } else {
        short* O = (mat == 0) ? Qo : So;
        #pragma unroll
        for (int c4 = 0; c4 < 4; ++c4) {
          const int col = ch * 64 + c4 * 16 + mm;
          #pragma unroll
          for (int t = 0; t < 2; ++t) {
            #pragma unroll
            for (int r = 0; r < 4; ++r) {
              int row = rowbase + t * 16 + quad * 4 + r;
              if (row < N_NODES)
                ((__hip_bfloat16*)O)[(size_t)row * 128 + col] = __float2bfloat16(acc[c4][t][r]);
            }
          }
        }
      }
    }
    if (s + 1 < STEPS) __syncthreads();
  }
}

// ---------------- D: layer-1 gemm + bucket edge scatter fused (R9) ----------------
__global__ __launch_bounds__(256)
void scatter_gemm1(const int* __restrict__ ei, const unsigned short* __restrict__ rank,
                   int* __restrict__ ssrc,
                   const float* __restrict__ X,
                   const short* __restrict__ w1q, const short* __restrict__ w1k,
                   const short* __restrict__ w1v, const short* __restrict__ w1s,
                   const float* __restrict__ b1q, const float* __restrict__ b1k,
                   const float* __restrict__ b1v, const float* __restrict__ b1s,
                   short* Qb, unsigned char* KV8, short* Sb)
{
  __shared__ short lds[2 * 64 * 128];   // 32 KB (2 x 16KB chunk buffers)
  int bx = blockIdx.x;
  if (bx >= NB_GEMM) {
    int e0 = (bx - NB_GEMM) * 1024 + threadIdx.x * 4;
    if (e0 >= N_EDGES) return;
    if (e0 + 3 < N_EDGES) {
      int4 sv = *(const int4*)(ei + e0);
      int4 dv = *(const int4*)(ei + N_EDGES + e0);
      ushort4 rv = *(const ushort4*)(rank + e0);
      if (rv.x < BUCKET) ssrc[(clamp_id(dv.x) << 6) + rv.x] = clamp_id(sv.x);
      if (rv.y < BUCKET) ssrc[(clamp_id(dv.y) << 6) + rv.y] = clamp_id(sv.y);
      if (rv.z < BUCKET) ssrc[(clamp_id(dv.z) << 6) + rv.z] = clamp_id(sv.z);
      if (rv.w < BUCKET) ssrc[(clamp_id(dv.w) << 6) + rv.w] = clamp_id(sv.w);
    } else {
      for (int j = 0; j < 4; ++j) {
        int e = e0 + j;
        if (e < N_EDGES) {
          unsigned short r = rank[e];
          if (r < BUCKET)
            ssrc[(clamp_id(ei[N_EDGES + e]) << 6) + r] = clamp_id(ei[e]);
        }
      }
    }
    return;
  }
  gemm_body<IN_CH, 1>(bx, X, w1q, w1k, w1v, w1s, b1q, b1k, b1v, b1s,
                      Qb, KV8, Sb, lds);
}

// ---------------- attention (R11: bucket ssrc in one wave load, 2-deep KV) ----------------
// R13: POOL variant — layer-2 H feeds ONLY pooling, so instead of writing 12.8MB
// of H and re-reading it in pool_partial, the sub==0 lanes atomicAdd their relu'd
// row directly into pooled[g] (128 fire-and-forget atomics/dst, 8192 L2-resident
// addresses). Kills a dispatch + 25.6MB of traffic.
template<bool POOL>
__global__ __launch_bounds__(256)
void attn_kernel(const unsigned short* __restrict__ Q, const unsigned char* __restrict__ KV8,
                 const unsigned short* S, const int* __restrict__ cnt,
                 const int* __restrict__ ssrc, unsigned short* H,
                 const int* __restrict__ batch, float* __restrict__ pooled)
{
  const int dst = blockIdx.x * 4 + (threadIdx.x >> 6);
  if (dst >= N_NODES) return;               // wave-uniform
  const int lane = threadIdx.x & 63;
  const int sub  = lane >> 4;               // edge slot 0..3
  const int cl   = lane & 15;               // 8 channels per lane

  const float qs = 0.17677669529663687f * 1.4426950408889634f;  // 1/sqrt(32)*log2(e)
  uint4 qw = *(const uint4*)(Q + (size_t)dst * 128 + cl * 8);
  uint4 sw = *(const uint4*)(S + (size_t)dst * 128 + cl * 8);   // hoisted skip row
  f32x2 q2[4], a2[4];
  #pragma unroll
  for (int i = 0; i < 4; ++i) {
    unsigned w = ((unsigned*)&qw)[i];
    f32x2 t; t.x = bfbits2f(w & 0xffffu) * qs; t.y = bfhi2f(w) * qs;
    q2[i] = t;
    a2[i].x = 0.f; a2[i].y = 0.f;
  }
  float s = 0.f;

  const int deg = min(cnt[dst], BUCKET);
  const int e0 = dst << 6;
  const int iters = (deg + 3) >> 2;

  // whole bucket in one coalesced load; slots >= deg masked via ph=0 (src 0 safe).
  int allsrc = (lane < deg) ? ssrc[e0 + lane] : 0;

  if (iters > 0) {
    auto kvload = [&](int it) -> uint4 {
      int sidx = __shfl(allsrc, 4 * it + sub, 64);
      return *(const uint4*)(KV8 + (size_t)sidx * 256 + cl * 16);
    };
    uint4 kva = kvload(0);
    uint4 kvb = kvload(1);   // harmless row-0 read when iters==1

    for (int it = 0; it < iters; ++it) {
      uint4 kv = kva;
      kva = kvb;
      if (it + 2 < iters) kvb = kvload(it + 2);   // 2-deep in flight
      const float ph = (4 * it + sub < deg) ? 1.f : 0.f;
      // kv.x = K ch 0-3, kv.y = K ch 4-7, kv.z = V ch 0-3, kv.w = V ch 4-7.
      f32x2 k0 = fp8pair<false>(kv.x), k1 = fp8pair<true>(kv.x);
      f32x2 k2 = fp8pair<false>(kv.y), k3 = fp8pair<true>(kv.y);
      f32x2 zz; zz.x = 0.f; zz.y = 0.f;
      f32x2 dd = pkfma(q2[0], k0, zz);
      dd = pkfma(q2[1], k1, dd);
      dd = pkfma(q2[2], k2, dd);
      dd = pkfma(q2[3], k3, dd);
      float d = quad_sum(dd.x + dd.y);      // 4-lane head reduce on the VALU (DPP)
      float p = exp2f(d) * ph;
      s += p;
      f32x2 p2; p2.x = p; p2.y = p;
      f32x2 v0 = fp8pair<false>(kv.z), v1 = fp8pair<true>(kv.z);
      f32x2 v2 = fp8pair<false>(kv.w), v3 = fp8pair<true>(kv.w);
      a2[0] = pkfma(p2, v0, a2[0]);
      a2[1] = pkfma(p2, v1, a2[1]);
      a2[2] = pkfma(p2, v2, a2[2]);
      a2[3] = pkfma(p2, v3, a2[3]);
    }
  }

  s += __shfl_xor(s, 16, 64);
  s += __shfl_xor(s, 32, 64);
  #pragma unroll
  for (int i = 0; i < 4; ++i) {
    f32x2 t;
    t.x = __shfl_xor(a2[i].x, 16, 64);
    t.y = __shfl_xor(a2[i].y, 16, 64);
    a2[i] = pkadd(a2[i], t);
    t.x = __shfl_xor(a2[i].x, 32, 64);
    t.y = __shfl_xor(a2[i].y, 32, 64);
    a2[i] = pkadd(a2[i], t);
  }
  const float inv = (s > 0.f) ? (1.0f / s) : 0.f;

  if (sub == 0) {
    if (POOL) {
      const int g = min(max(batch[dst], 0), N_GRAPHS - 1);
      #pragma unroll
      for (int i = 0; i < 4; ++i) {
        unsigned w = ((unsigned*)&sw)[i];
        float o0 = fmaxf(a2[i].x * inv + bfbits2f(w & 0xffffu), 0.f);
        float o1 = fmaxf(a2[i].y * inv + bfhi2f(w), 0.f);
        atomicAdd(&pooled[g * 128 + cl * 8 + 2 * i], o0);
        atomicAdd(&pooled[g * 128 + cl * 8 + 2 * i + 1], o1);
      }
    } else {
      uint4 ow;
      #pragma unroll
      for (int i = 0; i < 4; ++i) {
        unsigned w = ((unsigned*)&sw)[i];
        float o0 = fmaxf(a2[i].x * inv + bfbits2f(w & 0xffffu), 0.f);
        float o1 = fmaxf(a2[i].y * inv + bfhi2f(w), 0.f);
        ((unsigned*)&ow)[i] = (unsigned)f2bfu(o0) | ((unsigned)f2bfu(o1) << 16);
      }
      *(uint4*)(H + (size_t)dst * 128 + cl * 8) = ow;
    }
  }
}

// ---------------- F: layer-2 gemm ----------------
__global__ __launch_bounds__(256)
void gemm2(const short* __restrict__ X,
           const short* __restrict__ w2q, const short* __restrict__ w2k,
           const short* __restrict__ w2v, const short* __restrict__ w2s,
           const float* __restrict__ b2q, const float* __restrict__ b2k,
           const float* __restrict__ b2v, const float* __restrict__ b2s,
           short* Qb, unsigned char* KV8, short* Sb)
{
  __shared__ short lds[2 * 64 * 128];  // 32 KB (2 x 16KB chunk buffers)
  gemm_body<HID_CH, 0>(blockIdx.x, X, w2q, w2k, w2v, w2s, b2q, b2k, b2v, b2s,
                       Qb, KV8, Sb, lds);
}

// ---------------- pool final (R13: partial sums now inlined in attn2) ----------------
__global__ __launch_bounds__(128)
void pool_final(const float* __restrict__ pooled, const int* __restrict__ gstart,
                const float* __restrict__ Wl, const float* __restrict__ bl,
                float* __restrict__ out)
{
  const int g = blockIdx.x, t = threadIdx.x;
  __shared__ float r0[128], r1[128];
  const int len = gstart[g + 1] - gstart[g];
  const float inv = 1.0f / (float)max(len, 1);
  const float pc = pooled[g * 128 + t] * inv;
  r0[t] = pc * Wl[t * 2 + 0];
  r1[t] = pc * Wl[t * 2 + 1];
  __syncthreads();
  for (int o = 64; o > 0; o >>= 1) {
    if (t < o) { r0[t] += r0[t + o]; r1[t] += r1[t + o]; }
    __syncthreads();
  }
  if (t == 0) {
    out[g * 2 + 0] = r0[0] + bl[0];
    out[g * 2 + 1] = r1[0] + bl[1];
  }
}

// ---------------- launch ----------------

extern "C" void kernel_launch(void* const* d_in, const int* in_sizes, int n_in,
                              void* d_out, int out_size, void* d_ws, size_t ws_size,
                              hipStream_t stream) {
  uintptr_t base = (uintptr_t)d_ws;
  auto take = [&](size_t bytes) -> uintptr_t {
    uintptr_t p = base;
    base += (bytes + 255) & ~(size_t)255;
    return p;
  };

  // cnt + pooled + gstart first and contiguous: zeroed by ONE hipMemsetAsync.
  int*   cnt    = (int*)take((size_t)N_NODES * 4);
  float* pooled = (float*)take((size_t)N_GRAPHS * 128 * 4);
  int*   gstart = (int*)take((size_t)(N_GRAPHS + 1) * 4);
  int*   ssrc   = (int*)take((size_t)N_NODES * BUCKET * 4);   // 12.8 MB bucket CSR
  unsigned short* rank = (unsigned short*)take((size_t)N_EDGES * 2);
  short* Qb     = (short*)take((size_t)N_NODES * 128 * 2);
  unsigned char* KV8 = (unsigned char*)take((size_t)N_NODES * 256);  // fp8 interleaved K|V rows
  short* Sb     = (short*)take((size_t)N_NODES * 128 * 2);  // S / H / layer-2 X (in-place)
  short* wt1q   = (short*)take((size_t)IN_CH * 128 * 2);
  short* wt1k   = (short*)take((size_t)IN_CH * 128 * 2);
  short* wt1v   = (short*)take((size_t)IN_CH * 128 * 2);
  short* wt1s   = (short*)take((size_t)IN_CH * 128 * 2);
  short* wt2q   = (short*)take((size_t)HID_CH * 128 * 2);
  short* wt2k   = (short*)take((size_t)HID_CH * 128 * 2);
  short* wt2v   = (short*)take((size_t)HID_CH * 128 * 2);
  short* wt2s   = (short*)take((size_t)HID_CH * 128 * 2);

  const int* ei    = (const int*)d_in[1];   // int32 per harness contract
  const int* batch = (const int*)d_in[2];   // int32 per harness contract

  // Zero cnt..gstart span (contiguous, one DMA memset; graph-capturable).
  size_t zspan = (size_t)((char*)gstart + (size_t)(N_GRAPHS + 1) * 4 - (char*)cnt);
  hipMemsetAsync(cnt, 0, zspan, stream);

  // A: degree count (8/thread) + rank capture + weights + graph boundaries
  prep<<<NB_CNT8 + NB_CONV + NB_BND, 256, 0, stream>>>(
      ei, cnt, rank, batch, gstart,
      (const float*)d_in[3], (const float*)d_in[5], (const float*)d_in[7], (const float*)d_in[9],
      (const float*)d_in[11], (const float*)d_in[13], (const float*)d_in[15], (const float*)d_in[17],
      (__hip_bfloat16*)wt1q, (__hip_bfloat16*)wt1k, (__hip_bfloat16*)wt1v, (__hip_bfloat16*)wt1s,
      (__hip_bfloat16*)wt2q, (__hip_bfloat16*)wt2k, (__hip_bfloat16*)wt2v, (__hip_bfloat16*)wt2s);

  // D: layer-1 QKVS gemm (blocks first) + bucket edge scatter (backfill).
  scatter_gemm1<<<NB_GEMM + NB_CNT4, 256, 0, stream>>>(
      ei, rank, ssrc,
      (const float*)d_in[0],
      wt1q, wt1k, wt1v, wt1s,
      (const float*)d_in[4], (const float*)d_in[6], (const float*)d_in[8], (const float*)d_in[10],
      Qb, KV8, Sb);

  const int attn_grid = (N_NODES + 3) / 4;

  // E: layer-1 attention (writes H in place into Sb)
  attn_kernel<false><<<attn_grid, 256, 0, stream>>>(
      (const unsigned short*)Qb, KV8,
      (const unsigned short*)Sb, cnt, ssrc, (unsigned short*)Sb, batch, pooled);

  // F: layer-2 gemm (X = Sb, S in-place)
  gemm2<<<NB_GEMM, 256, 0, stream>>>(
      Sb, wt2q, wt2k, wt2v, wt2s,
      (const float*)d_in[12], (const float*)d_in[14], (const float*)d_in[16], (const float*)d_in[18],
      Qb, KV8, Sb);

  // G: layer-2 attention + fused pooling (atomics into pooled; no H write)
  attn_kernel<true><<<attn_grid, 256, 0, stream>>>(
      (const unsigned short*)Qb, KV8,
      (const unsigned short*)Sb, cnt, ssrc, (unsigned short*)Sb, batch, pooled);

  // Pool final: mean + linear readout
  pool_final<<<N_GRAPHS, 128, 0, stream>>>(pooled, gstart, (const float*)d_in[19],
                                           (const float*)d_in[20], (float*)d_out);
}

// Round 15
// 255.601 us; speedup vs baseline: 3.2913x; 3.2913x over previous
//
#include <hip/hip_runtime.h>
#include <hip/hip_bf16.h>
#include <cstdint>
#include <cstddef>

#define N_NODES 50000
#define N_EDGES 800000
#define IN_CH 64
#define HID_CH 128
#define N_GRAPHS 64

#define NB_CNT8 ((N_EDGES + 2047) / 2048)        // 391 (8 edges/thread, count)
#define NB_CNT4 ((N_EDGES + 1023) / 1024)        // 782 (4 edges/thread, scatter)
#define NB_GEMM ((N_NODES + 63) / 64)            // 782
#define W_ELEMS (4 * IN_CH * 128 + 4 * HID_CH * 128)  // 98304
#define NB_CONV ((W_ELEMS + 255) / 256)          // 384
#define NB_BND  ((N_NODES + 1 + 255) / 256)      // 196 (graph-boundary stage)
#define BUCKET 64                                 // edge slots per dst (P(deg>64)~1e-18)

typedef short s16x8 __attribute__((ext_vector_type(8)));
typedef float f32x4 __attribute__((ext_vector_type(4)));
typedef float f32x2 __attribute__((ext_vector_type(2)));

__device__ __forceinline__ float bf2f(__hip_bfloat16 v) { return __bfloat162float(v); }
__device__ __forceinline__ float bfbits2f(unsigned hs) {
  union { unsigned u; float f; } v; v.u = hs << 16; return v.f;
}
__device__ __forceinline__ float bfhi2f(unsigned w) {
  union { unsigned u; float f; } v; v.u = w & 0xffff0000u; return v.f;
}
__device__ __forceinline__ short f2bfs(float f) {
  __hip_bfloat16 h = __float2bfloat16(f); return *(short*)&h;
}
__device__ __forceinline__ unsigned short f2bfu(float f) {
  __hip_bfloat16 h = __float2bfloat16(f); return *(unsigned short*)&h;
}
__device__ __forceinline__ int clamp_id(int v) {
  if (v < 0) v = 0;
  if (v >= N_NODES) v = N_NODES - 1;
  return v;
}

// fp8 e4m3 (OCP) pack/unpack via gfx950 HW converters (word-selects are immediates).
__device__ __forceinline__ unsigned char f2fp8(float v) {
  return (unsigned char)(__builtin_amdgcn_cvt_pk_fp8_f32(v, v, 0, false) & 0xff);
}
template<bool HI>
__device__ __forceinline__ f32x2 fp8pair(unsigned w) {
  return __builtin_amdgcn_cvt_pk_f32_fp8(w, HI);
}

// R6: packed 2-wide f32 math (CDNA VOP3P). hipcc does not emit these from scalar
// source; non-volatile asm so the scheduler can interleave them freely.
__device__ __forceinline__ f32x2 pkfma(f32x2 a, f32x2 b, f32x2 c) {
  f32x2 d;
  asm("v_pk_fma_f32 %0, %1, %2, %3" : "=v"(d) : "v"(a), "v"(b), "v"(c));
  return d;
}
__device__ __forceinline__ f32x2 pkadd(f32x2 a, f32x2 b) {
  f32x2 d;
  asm("v_pk_add_f32 %0, %1, %2" : "=v"(d) : "v"(a), "v"(b));
  return d;
}

// R7: 4-lane quad sum on the VALU via DPP quad_perm (hand-verified).
__device__ __forceinline__ float quad_sum(float d) {
  d += __int_as_float(__builtin_amdgcn_mov_dpp(__float_as_int(d), 0xB1, 0xf, 0xf, true));
  d += __int_as_float(__builtin_amdgcn_mov_dpp(__float_as_int(d), 0x4E, 0xf, 0xf, true));
  return d;
}

// R12: async global->LDS DMA, 16B/lane. LDS dest is wave-uniform base + lane*16.
__device__ __forceinline__ void gload_lds16(const void* g, void* l) {
  __builtin_amdgcn_global_load_lds(
      (const __attribute__((address_space(1))) unsigned int*)g,
      (__attribute__((address_space(3))) unsigned int*)l, 16, 0, 0);
}

// ---------------- A: degree-count(+rank) + weights + graph boundaries ----------------
// (R1: atomicAdd return value saved as intra-segment rank. R9: rank indexes a fixed
// 64-slot bucket per dst — no prefix scan. R10: gstart precomputed. R13-kept: count
// at 8 edges/thread for deeper MLP on the atomic chain.)
// R13 LESSON (841us regression, reverted): per-node->per-graph reduction via
// same-address atomics serializes (~780 adds/address); always use partial-sum trees.
__global__ __launch_bounds__(256)
void prep(const int* __restrict__ ei, int* __restrict__ cnt,
          unsigned short* __restrict__ rank,
          const int* __restrict__ batch, int* __restrict__ gstart,
          const float* __restrict__ w1q, const float* __restrict__ w1k,
          const float* __restrict__ w1v, const float* __restrict__ w1s,
          const float* __restrict__ w2q, const float* __restrict__ w2k,
          const float* __restrict__ w2v, const float* __restrict__ w2s,
          __hip_bfloat16* d1q, __hip_bfloat16* d1k, __hip_bfloat16* d1v, __hip_bfloat16* d1s,
          __hip_bfloat16* d2q, __hip_bfloat16* d2k, __hip_bfloat16* d2v, __hip_bfloat16* d2s)
{
  int bx = blockIdx.x;
  if (bx < NB_CNT8) {
    int e0 = bx * 2048 + threadIdx.x * 8;
    if (e0 >= N_EDGES) return;
    if (e0 + 7 < N_EDGES) {
      int4 dv0 = *(const int4*)(ei + N_EDGES + e0);
      int4 dv1 = *(const int4*)(ei + N_EDGES + e0 + 4);
      ushort4 ra, rb;
      ra.x = (unsigned short)atomicAdd(&cnt[clamp_id(dv0.x)], 1);
      ra.y = (unsigned short)atomicAdd(&cnt[clamp_id(dv0.y)], 1);
      ra.z = (unsigned short)atomicAdd(&cnt[clamp_id(dv0.z)], 1);
      ra.w = (unsigned short)atomicAdd(&cnt[clamp_id(dv0.w)], 1);
      rb.x = (unsigned short)atomicAdd(&cnt[clamp_id(dv1.x)], 1);
      rb.y = (unsigned short)atomicAdd(&cnt[clamp_id(dv1.y)], 1);
      rb.z = (unsigned short)atomicAdd(&cnt[clamp_id(dv1.z)], 1);
      rb.w = (unsigned short)atomicAdd(&cnt[clamp_id(dv1.w)], 1);
      *(ushort4*)(rank + e0) = ra;
      *(ushort4*)(rank + e0 + 4) = rb;
    } else {
      for (int j = 0; j < 8; ++j)
        if (e0 + j < N_EDGES)
          rank[e0 + j] = (unsigned short)atomicAdd(&cnt[clamp_id(ei[N_EDGES + e0 + j])], 1);
    }
    return;
  }
  if (bx < NB_CNT8 + NB_CONV) {
    int j = (bx - NB_CNT8) * 256 + threadIdx.x;
    if (j >= W_ELEMS) return;
    const float* S[8] = {w1q, w1k, w1v, w1s, w2q, w2k, w2v, w2s};
    __hip_bfloat16* D[8] = {d1q, d1k, d1v, d1s, d2q, d2k, d2v, d2s};
    int m, r;
    if (j < 4 * IN_CH * 128) { m = j >> 13; r = j & 8191; }
    else { int jj = j - 4 * IN_CH * 128; m = 4 + (jj >> 14); r = jj & 16383; }
    int k = r >> 7, c = r & 127;
    D[m][(((k >> 3) * 128 + c) << 3) + (k & 7)] = __float2bfloat16(S[m][r]);
    return;
  }
  // graph-boundary stage: gstart[g] = first i with batch[i] >= g; gstart[G] = N.
  int i = (bx - NB_CNT8 - NB_CONV) * 256 + threadIdx.x;
  if (i > N_NODES) return;
  int bl = (i > 0) ? min(max(batch[i - 1], 0), N_GRAPHS - 1) : -1;
  int bc = (i < N_NODES) ? min(max(batch[i], 0), N_GRAPHS - 1) : N_GRAPHS;
  for (int g = bl + 1; g <= bc; ++g) gstart[g] = i;
}

// ---------------- shared gemm body (R12: global_load_lds + 16KB-chunk dbuf) ----------------
// Outputs: mat0=Q (bf16, row 128), mat1=K, mat2=V -> KV8 row, mat3=S (bf16, row 128).
// R7: KV8 row INTERLEAVED in 16B groups (K ch 8g..8g+7 | V same) — attn reads one uint4.
// So may alias X (in-place per-row: A-frags register-resident before stores).
template<int KD, int XF32>
__device__ __forceinline__ void gemm_body(
    int bg, const void* X,
    const short* __restrict__ WTq, const short* __restrict__ WTk,
    const short* __restrict__ WTv, const short* __restrict__ WTs,
    const float* __restrict__ bq, const float* __restrict__ bk,
    const float* __restrict__ bv, const float* __restrict__ bs,
    short* Qo, unsigned char* KV8, short* So, short* lds /* 2 x 8192 shorts */)
{
  constexpr int KT = KD / 32;
  constexpr int HALVES = KD / 64;          // 16KB chunks per mat: 1 (gemm1) / 2 (gemm2)
  constexpr int STEPS = 4 * HALVES;
  const int tid  = threadIdx.x;
  const int wid  = tid >> 6;
  const int lane = tid & 63;
  const int quad = lane >> 4;
  const int mm   = lane & 15;
  const int rt   = wid & 1;
  const int ch   = wid >> 1;
  const int rowbase = bg * 64 + rt * 32;

  const short* wts[4] = {WTq, WTk, WTv, WTs};
  const float* bias[4] = {bq, bk, bv, bs};

  auto stage = [&](int s) {
    const short* src = wts[s / HALVES] + (s % HALVES) * 8192;
    short* dstb = lds + (s & 1) * 8192;
    #pragma unroll
    for (int i = 0; i < 4; ++i)
      gload_lds16(src + (size_t)(i * 256 + tid) * 8,
                  dstb + (size_t)(i * 256 + wid * 64) * 8);
  };

  stage(0);

  s16x8 afrag[2][KT];
  #pragma unroll
  for (int t = 0; t < 2; ++t) {
    const int arow = rowbase + t * 16 + mm;
    if (arow < N_NODES) {
      if (XF32) {
        const float* xp = (const float*)X + (size_t)arow * KD;
        #pragma unroll
        for (int kt = 0; kt < KT; ++kt) {
          const float4* p = (const float4*)(xp + kt * 32 + quad * 8);
          float4 a = p[0], b = p[1];
          s16x8 fr;
          fr[0] = f2bfs(a.x); fr[1] = f2bfs(a.y); fr[2] = f2bfs(a.z); fr[3] = f2bfs(a.w);
          fr[4] = f2bfs(b.x); fr[5] = f2bfs(b.y); fr[6] = f2bfs(b.z); fr[7] = f2bfs(b.w);
          afrag[t][kt] = fr;
        }
      } else {
        const short* xp = (const short*)X + (size_t)arow * KD;
        #pragma unroll
        for (int kt = 0; kt < KT; ++kt)
          afrag[t][kt] = *(const s16x8*)(xp + kt * 32 + quad * 8);
      }
    } else {
      #pragma unroll
      for (int kt = 0; kt < KT; ++kt)
        afrag[t][kt] = (s16x8){0,0,0,0,0,0,0,0};
    }
  }

  __syncthreads();   // drains stage(0); afrag loads overlapped it

  f32x4 acc[4][2];
  #pragma unroll
  for (int s = 0; s < STEPS; ++s) {
    const int mat  = s / HALVES;
    const int half = s % HALVES;
    const short* bufp = lds + (s & 1) * 8192;

    if (half == 0) {
      #pragma unroll
      for (int c4 = 0; c4 < 4; ++c4) {
        float b = bias[mat][ch * 64 + c4 * 16 + mm];
        f32x4 av = {b, b, b, b};
        acc[c4][0] = av; acc[c4][1] = av;
      }
    }
    if (s + 1 < STEPS) stage(s + 1);   // issue next chunk BEFORE compute

    #pragma unroll
    for (int ktl = 0; ktl < 2; ++ktl) {
      #pragma unroll
      for (int c4 = 0; c4 < 4; ++c4) {
        s16x8 bfrag = *(const s16x8*)(bufp + ((((ktl * 4 + quad) << 7) + ch * 64 + c4 * 16 + mm) << 3));
        acc[c4][0] = __builtin_amdgcn_mfma_f32_16x16x32_bf16(afrag[0][half * 2 + ktl], bfrag, acc[c4][0], 0, 0, 0);
        acc[c4][1] = __builtin_amdgcn_mfma_f32_16x16x32_bf16(afrag[1][half * 2 + ktl], bfrag, acc[c4][1], 0, 0, 0);
      }
    }

    if (half == HALVES - 1) {
      if (mat == 1 || mat == 2) {
        const int voff = (mat == 2) ? 8 : 0;
        #pragma unroll
        for (int c4 = 0; c4 < 4; ++c4) {
          const int col = ch * 64 + c4 * 16 + mm;
          const int bpos = ((col >> 3) << 4) + voff + (col & 7);  // interleaved KV byte
          #pragma unroll
          for (int t = 0; t < 2; ++t) {
            #pragma unroll
            for (int r = 0; r < 4; ++r) {
              int row = rowbase + t * 16 + quad * 4 + r;
              if (row < N_NODES)
                KV8[(size_t)row * 256 + bpos] = f2fp8(acc[c4][t][r]);
            }
          }
        }
      } else {
        short* O = (mat == 0) ? Qo : So;
        #pragma unroll
        for (int c4 = 0; c4 < 4; ++c4) {
          const int col = ch * 64 + c4 * 16 + mm;
          #pragma unroll
          for (int t = 0; t < 2; ++t) {
            #pragma unroll
            for (int r = 0; r < 4; ++r) {
              int row = rowbase + t * 16 + quad * 4 + r;
              if (row < N_NODES)
                ((__hip_bfloat16*)O)[(size_t)row * 128 + col] = __float2bfloat16(acc[c4][t][r]);
            }
          }
        }
      }
    }
    if (s + 1 < STEPS) __syncthreads();
  }
}

// ---------------- D: layer-1 gemm + bucket edge scatter fused (R9) ----------------
__global__ __launch_bounds__(256)
void scatter_gemm1(const int* __restrict__ ei, const unsigned short* __restrict__ rank,
                   int* __restrict__ ssrc,
                   const float* __restrict__ X,
                   const short* __restrict__ w1q, const short* __restrict__ w1k,
                   const short* __restrict__ w1v, const short* __restrict__ w1s,
                   const float* __restrict__ b1q, const float* __restrict__ b1k,
                   const float* __restrict__ b1v, const float* __restrict__ b1s,
                   short* Qb, unsigned char* KV8, short* Sb)
{
  __shared__ short lds[2 * 64 * 128];   // 32 KB (2 x 16KB chunk buffers)
  int bx = blockIdx.x;
  if (bx >= NB_GEMM) {
    int e0 = (bx - NB_GEMM) * 1024 + threadIdx.x * 4;
    if (e0 >= N_EDGES) return;
    if (e0 + 3 < N_EDGES) {
      int4 sv = *(const int4*)(ei + e0);
      int4 dv = *(const int4*)(ei + N_EDGES + e0);
      ushort4 rv = *(const ushort4*)(rank + e0);
      if (rv.x < BUCKET) ssrc[(clamp_id(dv.x) << 6) + rv.x] = clamp_id(sv.x);
      if (rv.y < BUCKET) ssrc[(clamp_id(dv.y) << 6) + rv.y] = clamp_id(sv.y);
      if (rv.z < BUCKET) ssrc[(clamp_id(dv.z) << 6) + rv.z] = clamp_id(sv.z);
      if (rv.w < BUCKET) ssrc[(clamp_id(dv.w) << 6) + rv.w] = clamp_id(sv.w);
    } else {
      for (int j = 0; j < 4; ++j) {
        int e = e0 + j;
        if (e < N_EDGES) {
          unsigned short r = rank[e];
          if (r < BUCKET)
            ssrc[(clamp_id(ei[N_EDGES + e]) << 6) + r] = clamp_id(ei[e]);
        }
      }
    }
    return;
  }
  gemm_body<IN_CH, 1>(bx, X, w1q, w1k, w1v, w1s, b1q, b1k, b1v, b1s,
                      Qb, KV8, Sb, lds);
}

// ---------------- attention (R11-verified: bucket ssrc in one wave load, 2-deep KV) ----------------
// (R13's template<POOL> fusion reverted: atomic fan-in serialized + template
// co-compilation dropped VGPR to 28 -> spills. This is the exact R12 kernel.)
__global__ __launch_bounds__(256)
void attn_kernel(const unsigned short* __restrict__ Q, const unsigned char* __restrict__ KV8,
                 const unsigned short* S, const int* __restrict__ cnt,
                 const int* __restrict__ ssrc, unsigned short* H)
{
  const int dst = blockIdx.x * 4 + (threadIdx.x >> 6);
  if (dst >= N_NODES) return;               // wave-uniform
  const int lane = threadIdx.x & 63;
  const int sub  = lane >> 4;               // edge slot 0..3
  const int cl   = lane & 15;               // 8 channels per lane

  const float qs = 0.17677669529663687f * 1.4426950408889634f;  // 1/sqrt(32)*log2(e)
  uint4 qw = *(const uint4*)(Q + (size_t)dst * 128 + cl * 8);
  uint4 sw = *(const uint4*)(S + (size_t)dst * 128 + cl * 8);   // hoisted skip row
  f32x2 q2[4], a2[4];
  #pragma unroll
  for (int i = 0; i < 4; ++i) {
    unsigned w = ((unsigned*)&qw)[i];
    f32x2 t; t.x = bfbits2f(w & 0xffffu) * qs; t.y = bfhi2f(w) * qs;
    q2[i] = t;
    a2[i].x = 0.f; a2[i].y = 0.f;
  }
  float s = 0.f;

  const int deg = min(cnt[dst], BUCKET);
  const int e0 = dst << 6;
  const int iters = (deg + 3) >> 2;

  // whole bucket in one coalesced load; slots >= deg masked via ph=0 (src 0 safe).
  int allsrc = (lane < deg) ? ssrc[e0 + lane] : 0;

  if (iters > 0) {
    auto kvload = [&](int it) -> uint4 {
      int sidx = __shfl(allsrc, 4 * it + sub, 64);
      return *(const uint4*)(KV8 + (size_t)sidx * 256 + cl * 16);
    };
    uint4 kva = kvload(0);
    uint4 kvb = kvload(1);   // harmless row-0 read when iters==1

    for (int it = 0; it < iters; ++it) {
      uint4 kv = kva;
      kva = kvb;
      if (it + 2 < iters) kvb = kvload(it + 2);   // 2-deep in flight
      const float ph = (4 * it + sub < deg) ? 1.f : 0.f;
      // kv.x = K ch 0-3, kv.y = K ch 4-7, kv.z = V ch 0-3, kv.w = V ch 4-7.
      f32x2 k0 = fp8pair<false>(kv.x), k1 = fp8pair<true>(kv.x);
      f32x2 k2 = fp8pair<false>(kv.y), k3 = fp8pair<true>(kv.y);
      f32x2 zz; zz.x = 0.f; zz.y = 0.f;
      f32x2 dd = pkfma(q2[0], k0, zz);
      dd = pkfma(q2[1], k1, dd);
      dd = pkfma(q2[2], k2, dd);
      dd = pkfma(q2[3], k3, dd);
      float d = quad_sum(dd.x + dd.y);      // 4-lane head reduce on the VALU (DPP)
      float p = exp2f(d) * ph;
      s += p;
      f32x2 p2; p2.x = p; p2.y = p;
      f32x2 v0 = fp8pair<false>(kv.z), v1 = fp8pair<true>(kv.z);
      f32x2 v2 = fp8pair<false>(kv.w), v3 = fp8pair<true>(kv.w);
      a2[0] = pkfma(p2, v0, a2[0]);
      a2[1] = pkfma(p2, v1, a2[1]);
      a2[2] = pkfma(p2, v2, a2[2]);
      a2[3] = pkfma(p2, v3, a2[3]);
    }
  }

  s += __shfl_xor(s, 16, 64);
  s += __shfl_xor(s, 32, 64);
  #pragma unroll
  for (int i = 0; i < 4; ++i) {
    f32x2 t;
    t.x = __shfl_xor(a2[i].x, 16, 64);
    t.y = __shfl_xor(a2[i].y, 16, 64);
    a2[i] = pkadd(a2[i], t);
    t.x = __shfl_xor(a2[i].x, 32, 64);
    t.y = __shfl_xor(a2[i].y, 32, 64);
    a2[i] = pkadd(a2[i], t);
  }
  const float inv = (s > 0.f) ? (1.0f / s) : 0.f;

  if (sub == 0) {
    uint4 ow;
    #pragma unroll
    for (int i = 0; i < 4; ++i) {
      unsigned w = ((unsigned*)&sw)[i];
      float o0 = fmaxf(a2[i].x * inv + bfbits2f(w & 0xffffu), 0.f);
      float o1 = fmaxf(a2[i].y * inv + bfhi2f(w), 0.f);
      ((unsigned*)&ow)[i] = (unsigned)f2bfu(o0) | ((unsigned)f2bfu(o1) << 16);
    }
    *(uint4*)(H + (size_t)dst * 128 + cl * 8) = ow;
  }
}

// ---------------- F: layer-2 gemm ----------------
__global__ __launch_bounds__(256)
void gemm2(const short* __restrict__ X,
           const short* __restrict__ w2q, const short* __restrict__ w2k,
           const short* __restrict__ w2v, const short* __restrict__ w2s,
           const float* __restrict__ b2q, const float* __restrict__ b2k,
           const float* __restrict__ b2v, const float* __restrict__ b2s,
           short* Qb, unsigned char* KV8, short* Sb)
{
  __shared__ short lds[2 * 64 * 128];  // 32 KB (2 x 16KB chunk buffers)
  gemm_body<HID_CH, 0>(blockIdx.x, X, w2q, w2k, w2v, w2s, b2q, b2k, b2v, b2s,
                       Qb, KV8, Sb, lds);
}

// ---------------- pooling (R10-verified: gstart loads, 4-way unrolled MLP) ----------------
__global__ __launch_bounds__(128)
void pool_partial(const __hip_bfloat16* __restrict__ H, const int* __restrict__ gstart,
                  float* __restrict__ pooled)
{
  const int g = blockIdx.x >> 4, p = blockIdx.x & 15, t = threadIdx.x;
  const int s = gstart[g];
  const int e = gstart[g + 1];
  const int len = e - s;
  if (len <= 0) return;
  const int chunk = (len + 15) >> 4;
  const int a = s + p * chunk;
  const int b = min(a + chunk, e);
  if (a >= b) return;
  float s0 = 0.f, s1 = 0.f, s2 = 0.f, s3 = 0.f;
  int i = a;
  for (; i + 3 < b; i += 4) {
    s0 += bf2f(H[(size_t)i * 128 + t]);
    s1 += bf2f(H[(size_t)(i + 1) * 128 + t]);
    s2 += bf2f(H[(size_t)(i + 2) * 128 + t]);
    s3 += bf2f(H[(size_t)(i + 3) * 128 + t]);
  }
  for (; i < b; ++i) s0 += bf2f(H[(size_t)i * 128 + t]);
  atomicAdd(&pooled[g * 128 + t], (s0 + s1) + (s2 + s3));
}

__global__ __launch_bounds__(128)
void pool_final(const float* __restrict__ pooled, const int* __restrict__ gstart,
                const float* __restrict__ Wl, const float* __restrict__ bl,
                float* __restrict__ out)
{
  const int g = blockIdx.x, t = threadIdx.x;
  __shared__ float r0[128], r1[128];
  const int len = gstart[g + 1] - gstart[g];
  const float inv = 1.0f / (float)max(len, 1);
  const float pc = pooled[g * 128 + t] * inv;
  r0[t] = pc * Wl[t * 2 + 0];
  r1[t] = pc * Wl[t * 2 + 1];
  __syncthreads();
  for (int o = 64; o > 0; o >>= 1) {
    if (t < o) { r0[t] += r0[t + o]; r1[t] += r1[t + o]; }
    __syncthreads();
  }
  if (t == 0) {
    out[g * 2 + 0] = r0[0] + bl[0];
    out[g * 2 + 1] = r1[0] + bl[1];
  }
}

// ---------------- launch ----------------

extern "C" void kernel_launch(void* const* d_in, const int* in_sizes, int n_in,
                              void* d_out, int out_size, void* d_ws, size_t ws_size,
                              hipStream_t stream) {
  uintptr_t base = (uintptr_t)d_ws;
  auto take = [&](size_t bytes) -> uintptr_t {
    uintptr_t p = base;
    base += (bytes + 255) & ~(size_t)255;
    return p;
  };

  // cnt + pooled + gstart first and contiguous: zeroed by ONE hipMemsetAsync.
  int*   cnt    = (int*)take((size_t)N_NODES * 4);
  float* pooled = (float*)take((size_t)N_GRAPHS * 128 * 4);
  int*   gstart = (int*)take((size_t)(N_GRAPHS + 1) * 4);
  int*   ssrc   = (int*)take((size_t)N_NODES * BUCKET * 4);   // 12.8 MB bucket CSR
  unsigned short* rank = (unsigned short*)take((size_t)N_EDGES * 2);
  short* Qb     = (short*)take((size_t)N_NODES * 128 * 2);
  unsigned char* KV8 = (unsigned char*)take((size_t)N_NODES * 256);  // fp8 interleaved K|V rows
  short* Sb     = (short*)take((size_t)N_NODES * 128 * 2);  // S / H / layer-2 X (in-place)
  short* wt1q   = (short*)take((size_t)IN_CH * 128 * 2);
  short* wt1k   = (short*)take((size_t)IN_CH * 128 * 2);
  short* wt1v   = (short*)take((size_t)IN_CH * 128 * 2);
  short* wt1s   = (short*)take((size_t)IN_CH * 128 * 2);
  short* wt2q   = (short*)take((size_t)HID_CH * 128 * 2);
  short* wt2k   = (short*)take((size_t)HID_CH * 128 * 2);
  short* wt2v   = (short*)take((size_t)HID_CH * 128 * 2);
  short* wt2s   = (short*)take((size_t)HID_CH * 128 * 2);

  const int* ei    = (const int*)d_in[1];   // int32 per harness contract
  const int* batch = (const int*)d_in[2];   // int32 per harness contract

  // Zero cnt..gstart span (contiguous, one DMA memset; graph-capturable).
  size_t zspan = (size_t)((char*)gstart + (size_t)(N_GRAPHS + 1) * 4 - (char*)cnt);
  hipMemsetAsync(cnt, 0, zspan, stream);

  // A: degree count (8/thread) + rank capture + weights + graph boundaries
  prep<<<NB_CNT8 + NB_CONV + NB_BND, 256, 0, stream>>>(
      ei, cnt, rank, batch, gstart,
      (const float*)d_in[3], (const float*)d_in[5], (const float*)d_in[7], (const float*)d_in[9],
      (const float*)d_in[11], (const float*)d_in[13], (const float*)d_in[15], (const float*)d_in[17],
      (__hip_bfloat16*)wt1q, (__hip_bfloat16*)wt1k, (__hip_bfloat16*)wt1v, (__hip_bfloat16*)wt1s,
      (__hip_bfloat16*)wt2q, (__hip_bfloat16*)wt2k, (__hip_bfloat16*)wt2v, (__hip_bfloat16*)wt2s);

  // D: layer-1 QKVS gemm (blocks first) + bucket edge scatter (backfill).
  scatter_gemm1<<<NB_GEMM + NB_CNT4, 256, 0, stream>>>(
      ei, rank, ssrc,
      (const float*)d_in[0],
      wt1q, wt1k, wt1v, wt1s,
      (const float*)d_in[4], (const float*)d_in[6], (const float*)d_in[8], (const float*)d_in[10],
      Qb, KV8, Sb);

  const int attn_grid = (N_NODES + 3) / 4;

  // E: layer-1 attention (writes H in place into Sb)
  attn_kernel<<<attn_grid, 256, 0, stream>>>(
      (const unsigned short*)Qb, KV8,
      (const unsigned short*)Sb, cnt, ssrc, (unsigned short*)Sb);

  // F: layer-2 gemm (X = Sb, S in-place)
  gemm2<<<NB_GEMM, 256, 0, stream>>>(
      Sb, wt2q, wt2k, wt2v, wt2s,
      (const float*)d_in[12], (const float*)d_in[14], (const float*)d_in[16], (const float*)d_in[18],
      Qb, KV8, Sb);

  // G: layer-2 attention (writes H in place into Sb)
  attn_kernel<<<attn_grid, 256, 0, stream>>>(
      (const unsigned short*)Qb, KV8,
      (const unsigned short*)Sb, cnt, ssrc, (unsigned short*)Sb);

  // Pool: 16 partials/graph (gstart loads, 4-wide MLP) then final linear
  pool_partial<<<N_GRAPHS * 16, 128, 0, stream>>>(
      (const __hip_bfloat16*)Sb, gstart, pooled);
  pool_final<<<N_GRAPHS, 128, 0, stream>>>(pooled, gstart, (const float*)d_in[19],
                                           (const float*)d_in[20], (float*)d_out);
}